// Round 2
// baseline (180.505 us; speedup 1.0000x reference)
//
#include <hip/hip_runtime.h>

// Detail_loss: loss = 0.25/(98*258*256) * sum_{n,h,w} ( |D[h][w+1]-D[h][w-1]| + |D[h+1][w]-D[h-1][w]| )
// where D[n,h,w] = sum_c (infer - ref)[n,c,h,w], zero outside [0,256)^2.
//
// R7: R6's sliding-window register pipeline was serialized by the compiler
// (VGPR_Count=40 proves no loads stayed in flight; warm==cold time -> pure
// latency-chain bound, 1.6 TB/s). Fix: eliminate ALL cross-iteration register
// state. One output row per wave, 25088 fully independent tasks. Each wave:
// 18 independent float4 loads (rows h-1,h,h+1 x 6 arrays, clamped + masked at
// edges) -> combine -> 2 shuffles -> wave reduce. Latency hidden by task
// parallelism (~4-6k resident waves), not intra-wave scheduling. Logical reads
// are 3x the input but rows are re-read by ADJACENT waves -> L1/L2 absorb;
// HBM-unique stays 154 MB (~25 us roofline). XCD-chunked block swizzle
// (6272 %% 8 == 0, bijective) keeps adjacent-row blocks on one XCD's L2.

#define W 256
#define NIMG 98
#define CH_STRIDE 65536              // 256*256 floats per channel
#define WAVES_PER_BLK 4
#define NROWS (NIMG * 256)           // 25088 row-tasks, 1 per wave
#define NBLK (NROWS / WAVES_PER_BLK) // 6272 blocks
#define NXCD 8
#define SCALE (0.25f / 6472704.0f)   // 0.25/(98*258*256)

struct Row6 { float4 a0, a1, a2, b0, b1, b2; };

// 6 independent float4 loads for one (already clamped) row offset.
__device__ __forceinline__ Row6 issue6(const float* __restrict__ xb,
                                       const float* __restrict__ yb, int ro) {
  Row6 r;
  r.a0 = *(const float4*)(xb + ro);
  r.a1 = *(const float4*)(xb + ro + CH_STRIDE);
  r.a2 = *(const float4*)(xb + ro + 2 * CH_STRIDE);
  r.b0 = *(const float4*)(yb + ro);
  r.b1 = *(const float4*)(yb + ro + CH_STRIDE);
  r.b2 = *(const float4*)(yb + ro + 2 * CH_STRIDE);
  return r;
}

// Channel-summed difference, masked (m = 0.f for padding rows; clamped loads
// read valid data then multiply to zero -> no uninitialized registers).
__device__ __forceinline__ float4 combine(const Row6& r, float m) {
  float4 d;
  d.x = m * ((r.a0.x - r.b0.x) + (r.a1.x - r.b1.x) + (r.a2.x - r.b2.x));
  d.y = m * ((r.a0.y - r.b0.y) + (r.a1.y - r.b1.y) + (r.a2.y - r.b2.y));
  d.z = m * ((r.a0.z - r.b0.z) + (r.a1.z - r.b1.z) + (r.a2.z - r.b2.z));
  d.w = m * ((r.a0.w - r.b0.w) + (r.a1.w - r.b1.w) + (r.a2.w - r.b2.w));
  return d;
}

__device__ __forceinline__ float row_task(const float* __restrict__ x,
                                          const float* __restrict__ y,
                                          int task, int lane) {
  const int n = task >> 8;         // image
  const int h = task & 255;        // output row

  const float* xb = x + (size_t)n * 3 * CH_STRIDE + (lane << 2);
  const float* yb = y + (size_t)n * 3 * CH_STRIDE + (lane << 2);

  const int hm = (h > 0)   ? h - 1 : 0;     // clamped; masked below
  const int hp = (h < 255) ? h + 1 : 255;

  // 18 independent loads, all issued before any use.
  Row6 rm = issue6(xb, yb, hm * W);
  Row6 rc = issue6(xb, yb, h  * W);
  Row6 rp = issue6(xb, yb, hp * W);

  float4 dm = combine(rm, (h > 0)   ? 1.f : 0.f);
  float4 dc = combine(rc, 1.f);
  float4 dp = combine(rp, (h < 255) ? 1.f : 0.f);

  // Horizontal: |D[w+1]-D[w-1]| for this lane's 4 columns of row h.
  float lm = __shfl_up(dc.w, 1);     // left neighbor's col 4L-1
  if (lane == 0) lm = 0.f;           // image col -1 zero pad
  float rr = __shfl_down(dc.x, 1);   // right neighbor's col 4L+4
  if (lane == 63) rr = 0.f;          // image col 256 zero pad
  float acc = fabsf(dc.y - lm) + fabsf(dc.z - dc.x)
            + fabsf(dc.w - dc.y) + fabsf(rr - dc.z);

  // Vertical: |D[h+1]-D[h-1]|, register-local.
  acc += fabsf(dp.x - dm.x) + fabsf(dp.y - dm.y)
       + fabsf(dp.z - dm.z) + fabsf(dp.w - dm.w);

  // Wave reduce.
  #pragma unroll
  for (int off = 32; off > 0; off >>= 1)
    acc += __shfl_down(acc, off, 64);
  return acc;
}

// Bijective XCD-chunked swizzle (NBLK % 8 == 0): consecutive logical blocks
// (adjacent rows) land on the same XCD -> row re-reads hit that XCD's L2.
__device__ __forceinline__ int swz_block(int bid) {
  const int chunk = NBLK / NXCD;     // 784
  return (bid % NXCD) * chunk + bid / NXCD;
}

__device__ __forceinline__ float block_body(const float* __restrict__ x,
                                            const float* __restrict__ y) {
  const int tid  = threadIdx.x;
  const int lane = tid & 63;
  const int wv   = tid >> 6;
  const int task = swz_block(blockIdx.x) * WAVES_PER_BLK + wv;

  float s = row_task(x, y, task, lane);

  __shared__ float ws[WAVES_PER_BLK];
  if (lane == 0) ws[wv] = s;
  __syncthreads();
  return ws[0] + ws[1] + ws[2] + ws[3];
}

__global__ __launch_bounds__(256) void detail_stage1(
    const float* __restrict__ x, const float* __restrict__ y,
    float* __restrict__ partial) {
  float s = block_body(x, y);
  if (threadIdx.x == 0) partial[blockIdx.x] = s;
}

__global__ __launch_bounds__(256) void detail_stage1_atomic(
    const float* __restrict__ x, const float* __restrict__ y,
    float* __restrict__ out) {
  float s = block_body(x, y);
  if (threadIdx.x == 0) atomicAdd(out, s * SCALE);
}

__global__ __launch_bounds__(256) void detail_stage2(
    const float* __restrict__ partial, float* __restrict__ out) {
  float acc = 0.f;
  for (int i = threadIdx.x; i < NBLK; i += 256) acc += partial[i];
  #pragma unroll
  for (int off = 32; off > 0; off >>= 1)
    acc += __shfl_down(acc, off, 64);
  __shared__ float ws[4];
  if ((threadIdx.x & 63) == 0) ws[threadIdx.x >> 6] = acc;
  __syncthreads();
  if (threadIdx.x == 0) out[0] = (ws[0] + ws[1] + ws[2] + ws[3]) * SCALE;
}

extern "C" void kernel_launch(void* const* d_in, const int* in_sizes, int n_in,
                              void* d_out, int out_size, void* d_ws, size_t ws_size,
                              hipStream_t stream) {
  const float* infer = (const float*)d_in[0];
  const float* ref   = (const float*)d_in[1];
  float* out = (float*)d_out;

  if (ws_size >= NBLK * sizeof(float)) {
    float* partial = (float*)d_ws;
    detail_stage1<<<NBLK, 256, 0, stream>>>(infer, ref, partial);
    detail_stage2<<<1, 256, 0, stream>>>(partial, out);
  } else {
    hipMemsetAsync(out, 0, sizeof(float), stream);
    detail_stage1_atomic<<<NBLK, 256, 0, stream>>>(infer, ref, out);
  }
}

// Round 3
// 172.844 us; speedup vs baseline: 1.0443x; 1.0443x over previous
//
#include <hip/hip_runtime.h>

// Detail_loss: loss = 0.25/(98*258*256) * sum_{n,h,w} ( |D[h][w+1]-D[h][w-1]| + |D[h+1][w]-D[h-1][w]| )
// where D[n,h,w] = sum_c (infer - ref)[n,c,h,w], zero outside [0,256)^2.
//
// R8: R6/R7 proved the compiler will never keep VGPR-destined loads in flight
// (VGPR_Count 40/36), and R7's counters show the memory system happily serves
// ~7.5 TB/s from L2/L3 when enough requests are outstanding (451 MB logical in
// 60us, warm == cold). R5 had hardware-queued loads (global_load_lds) but
// drained vmcnt(0) at a barrier every block. This version combines them:
// per-WAVE software pipeline, counted vmcnt, ZERO barriers in the loop.
//   - wave owns an 8-row band + private 12 KB LDS (2 slots x 6 KB, dbuf)
//   - 6 global_load_lds per row (1 KB each, no VGPR dest); 2 rows = 12 loads
//     permanently in flight; consume behind s_waitcnt vmcnt(6) (never 0
//     mid-loop)
//   - slot-reuse fenced by lgkmcnt(0) after the D-combine (ds_reads retired
//     before the same slot is re-staged)
//   - D rows in a 3-register rotating window (hand-unrolled, named regs);
//     horizontal term = 2 shuffles (R7 math, verified absmax 0)
// 48 KB/block -> 3 blocks/CU = 12 waves/CU x 12 KB in flight = 144 KB/CU
// outstanding. Logical traffic 193 MB (1.25x unique) at >=7.5 TB/s -> ~26 us.

#define W 256
#define NIMG 98
#define CH_STRIDE 65536              // 256*256 floats per channel
#define TH 8                         // output rows per band
#define NBAND (NIMG * 32)            // 3136 bands, 1 per wave
#define WAVES_PER_BLK 4
#define NBLK (NBAND / WAVES_PER_BLK) // 784 blocks
#define NXCD 8
#define SCALE (0.25f / 6472704.0f)   // 0.25/(98*258*256)

__device__ __forceinline__ void async_copy16(const float* g, float* l) {
  // One instruction: 64 lanes x 16 B = 1 KB row. LDS dest = wave-uniform base
  // + lane*16 (hardware); global address is per-lane.
  __builtin_amdgcn_global_load_lds(
      (const __attribute__((address_space(1))) void*)g,
      (__attribute__((address_space(3))) void*)l,
      16, 0, 0);
}

#define WAITVM6() asm volatile("s_waitcnt vmcnt(6)" ::: "memory")
#define WAITVM0() asm volatile("s_waitcnt vmcnt(0)" ::: "memory")
#define WAITLGKM0() asm volatile("s_waitcnt lgkmcnt(0)" ::: "memory")

// sm[wv][slot][array 0-5][col]; arrays 0-2 = x ch0-2, 3-5 = y ch0-2.
struct SmemT {
  float raw[WAVES_PER_BLK][2][6][W];   // 48 KB
  float ws[WAVES_PER_BLK];
};

__device__ __forceinline__ float4 combine_slot(const float (*slot)[W],
                                               int lane4, float m) {
  const float4 a0 = *(const float4*)&slot[0][lane4];
  const float4 a1 = *(const float4*)&slot[1][lane4];
  const float4 a2 = *(const float4*)&slot[2][lane4];
  const float4 b0 = *(const float4*)&slot[3][lane4];
  const float4 b1 = *(const float4*)&slot[4][lane4];
  const float4 b2 = *(const float4*)&slot[5][lane4];
  float4 d;
  d.x = m * ((a0.x - b0.x) + (a1.x - b1.x) + (a2.x - b2.x));
  d.y = m * ((a0.y - b0.y) + (a1.y - b1.y) + (a2.y - b2.y));
  d.z = m * ((a0.z - b0.z) + (a1.z - b1.z) + (a2.z - b2.z));
  d.w = m * ((a0.w - b0.w) + (a1.w - b1.w) + (a2.w - b2.w));
  return d;
}

__device__ __forceinline__ float block_body(const float* __restrict__ x,
                                            const float* __restrict__ y,
                                            SmemT& sm) {
  const int tid  = threadIdx.x;
  const int lane = tid & 63;
  const int wv   = tid >> 6;
  const int lane4 = lane << 2;

  // Bijective XCD-chunked swizzle (784 % 8 == 0): consecutive bands share an
  // XCD L2 so the 2-row halo re-reads between vertical neighbors hit L2.
  const int b    = blockIdx.x;
  const int swz  = (b % NXCD) * (NBLK / NXCD) + b / NXCD;
  const int band = swz * WAVES_PER_BLK + wv;
  const int n     = band >> 5;      // image
  const int strip = band & 31;
  const int r0    = strip * TH;

  const float* xb = x + (size_t)n * 3 * CH_STRIDE + lane4;
  const float* yb = y + (size_t)n * 3 * CH_STRIDE + lane4;

  // Stage halo row lr (global row r0-1+lr, clamped; OOB masked in combine).
  #define STAGE(lr, slot) do {                                        \
    int g_ = r0 - 1 + (lr);                                           \
    g_ = (g_ < 0) ? 0 : (g_ > 255 ? 255 : g_);                        \
    const float* gx_ = xb + g_ * W;                                   \
    const float* gy_ = yb + g_ * W;                                   \
    async_copy16(gx_,                  &sm.raw[wv][slot][0][0]);      \
    async_copy16(gx_ + CH_STRIDE,      &sm.raw[wv][slot][1][0]);      \
    async_copy16(gx_ + 2 * CH_STRIDE,  &sm.raw[wv][slot][2][0]);      \
    async_copy16(gy_,                  &sm.raw[wv][slot][3][0]);      \
    async_copy16(gy_ + CH_STRIDE,      &sm.raw[wv][slot][4][0]);      \
    async_copy16(gy_ + 2 * CH_STRIDE,  &sm.raw[wv][slot][5][0]);      \
  } while (0)

  float acc = 0.f;
  float4 dA, dB, dC;

  // Accumulate output row whose D is Dm1: horizontal on Dm1 (2 shuffles),
  // vertical |Dc - Dm2| (register-local). Math verified in R7 (absmax 0).
  #define ACCROW(Dm2, Dm1, Dc) do {                                   \
    float lm_ = __shfl_up((Dm1).w, 1);                                \
    if (lane == 0) lm_ = 0.f;                                         \
    float rr_ = __shfl_down((Dm1).x, 1);                              \
    if (lane == 63) rr_ = 0.f;                                        \
    acc += fabsf((Dm1).y - lm_) + fabsf((Dm1).z - (Dm1).x)           \
         + fabsf((Dm1).w - (Dm1).y) + fabsf(rr_ - (Dm1).z);          \
    acc += fabsf((Dc).x - (Dm2).x) + fabsf((Dc).y - (Dm2).y)         \
         + fabsf((Dc).z - (Dm2).z) + fabsf((Dc).w - (Dm2).w);        \
  } while (0)

  // mask: staged row lr is real image row r0-1+lr? (only ends can be OOB)
  #define MASK(lr) (((lr) == 0) ? (r0 > 0 ? 1.f : 0.f)                \
                  : ((lr) == 9) ? (r0 < 248 ? 1.f : 0.f) : 1.f)

  // ---- Prologue: 2 rows (12 loads) in flight.
  STAGE(0, 0);
  STAGE(1, 1);

  // ---- Pipelined iterations. Per iter k: wait oldest row (vmcnt(6)),
  // combine D(k) from slot k&1, fence ds_reads (lgkmcnt 0), re-stage lr k+2
  // into the just-freed slot, then accumulate (register-only).
  #define ITER(k, Rm2, Rm1, Rc, DO_ACC, DO_ISSUE)                     \
    do {                                                              \
      if ((k) < 9) { WAITVM6(); } else { WAITVM0(); }                 \
      Rc = combine_slot(sm.raw[wv][(k) & 1], lane4, MASK(k));         \
      WAITLGKM0();                                                    \
      if (DO_ISSUE) STAGE((k) + 2, (k) & 1);                          \
      if (DO_ACC) ACCROW(Rm2, Rm1, Rc);                               \
    } while (0)

  ITER(0, dA, dA, dA, 0, 1);
  ITER(1, dA, dA, dB, 0, 1);
  ITER(2, dA, dB, dC, 1, 1);
  ITER(3, dB, dC, dA, 1, 1);
  ITER(4, dC, dA, dB, 1, 1);
  ITER(5, dA, dB, dC, 1, 1);
  ITER(6, dB, dC, dA, 1, 1);
  ITER(7, dC, dA, dB, 1, 1);
  ITER(8, dA, dB, dC, 1, 0);
  ITER(9, dB, dC, dA, 1, 0);

  #undef ITER
  #undef MASK
  #undef ACCROW
  #undef STAGE

  // ---- Wave reduce, then one barrier for the cross-wave block sum.
  #pragma unroll
  for (int off = 32; off > 0; off >>= 1)
    acc += __shfl_down(acc, off, 64);
  if (lane == 0) sm.ws[wv] = acc;
  __syncthreads();
  return sm.ws[0] + sm.ws[1] + sm.ws[2] + sm.ws[3];
}

__global__ __launch_bounds__(256) void detail_stage1(
    const float* __restrict__ x, const float* __restrict__ y,
    float* __restrict__ partial) {
  __shared__ SmemT sm;
  float s = block_body(x, y, sm);
  if (threadIdx.x == 0) partial[blockIdx.x] = s;
}

__global__ __launch_bounds__(256) void detail_stage1_atomic(
    const float* __restrict__ x, const float* __restrict__ y,
    float* __restrict__ out) {
  __shared__ SmemT sm;
  float s = block_body(x, y, sm);
  if (threadIdx.x == 0) atomicAdd(out, s * SCALE);
}

__global__ __launch_bounds__(256) void detail_stage2(
    const float* __restrict__ partial, float* __restrict__ out) {
  float acc = 0.f;
  for (int i = threadIdx.x; i < NBLK; i += 256) acc += partial[i];
  #pragma unroll
  for (int off = 32; off > 0; off >>= 1)
    acc += __shfl_down(acc, off, 64);
  __shared__ float ws[4];
  if ((threadIdx.x & 63) == 0) ws[threadIdx.x >> 6] = acc;
  __syncthreads();
  if (threadIdx.x == 0) out[0] = (ws[0] + ws[1] + ws[2] + ws[3]) * SCALE;
}

extern "C" void kernel_launch(void* const* d_in, const int* in_sizes, int n_in,
                              void* d_out, int out_size, void* d_ws, size_t ws_size,
                              hipStream_t stream) {
  const float* infer = (const float*)d_in[0];
  const float* ref   = (const float*)d_in[1];
  float* out = (float*)d_out;

  if (ws_size >= NBLK * sizeof(float)) {
    float* partial = (float*)d_ws;
    detail_stage1<<<NBLK, 256, 0, stream>>>(infer, ref, partial);
    detail_stage2<<<1, 256, 0, stream>>>(partial, out);
  } else {
    hipMemsetAsync(out, 0, sizeof(float), stream);
    detail_stage1_atomic<<<NBLK, 256, 0, stream>>>(infer, ref, out);
  }
}